// Round 1
// 1588.163 us; speedup vs baseline: 1.1620x; 1.1620x over previous
//
#include <hip/hip_runtime.h>
#include <stdint.h>
#include <math.h>

// Problem constants (fixed by the reference)
#define B_ROWS 131072
#define INP 5
#define HID 64
#define NEXP 40
#define OUT_D 5

// f32 fast-path argmax safety margin; error bound ~3e-5 -> 130x headroom.
#define MARGIN 4e-3f
#define LISTCAP 16384

typedef short bf16x8 __attribute__((ext_vector_type(8)));
typedef float f32x16 __attribute__((ext_vector_type(16)));

__device__ __forceinline__ uint32_t rotl32(uint32_t v, int d) {
  return (v << d) | (v >> (32 - d));
}

// JAX threefry2x32 (20 rounds), matches jax._src.prng lowering exactly.
__device__ __forceinline__ void threefry2x32(uint32_t ks0, uint32_t ks1,
                                             uint32_t x0, uint32_t x1,
                                             uint32_t& o0, uint32_t& o1) {
  uint32_t ks2 = ks0 ^ ks1 ^ 0x1BD11BDAu;
  x0 += ks0; x1 += ks1;
  x0 += x1; x1 = rotl32(x1, 13); x1 ^= x0;
  x0 += x1; x1 = rotl32(x1, 15); x1 ^= x0;
  x0 += x1; x1 = rotl32(x1, 26); x1 ^= x0;
  x0 += x1; x1 = rotl32(x1, 6);  x1 ^= x0;
  x0 += ks1; x1 += ks2 + 1u;
  x0 += x1; x1 = rotl32(x1, 17); x1 ^= x0;
  x0 += x1; x1 = rotl32(x1, 29); x1 ^= x0;
  x0 += x1; x1 = rotl32(x1, 16); x1 ^= x0;
  x0 += x1; x1 = rotl32(x1, 24); x1 ^= x0;
  x0 += ks2; x1 += ks0 + 2u;
  x0 += x1; x1 = rotl32(x1, 13); x1 ^= x0;
  x0 += x1; x1 = rotl32(x1, 15); x1 ^= x0;
  x0 += x1; x1 = rotl32(x1, 26); x1 ^= x0;
  x0 += x1; x1 = rotl32(x1, 6);  x1 ^= x0;
  x0 += ks0; x1 += ks1 + 3u;
  x0 += x1; x1 = rotl32(x1, 17); x1 ^= x0;
  x0 += x1; x1 = rotl32(x1, 29); x1 ^= x0;
  x0 += x1; x1 = rotl32(x1, 16); x1 ^= x0;
  x0 += x1; x1 = rotl32(x1, 24); x1 ^= x0;
  x0 += ks1; x1 += ks2 + 4u;
  x0 += x1; x1 = rotl32(x1, 13); x1 ^= x0;
  x0 += x1; x1 = rotl32(x1, 15); x1 ^= x0;
  x0 += x1; x1 = rotl32(x1, 26); x1 ^= x0;
  x0 += x1; x1 = rotl32(x1, 6);  x1 ^= x0;
  x0 += ks2; x1 += ks0 + 5u;
  o0 = x0; o1 = x1;
}

__device__ __forceinline__ uint16_t f32_to_bf16(float f) {
  uint32_t u = __float_as_uint(f);
  u += 0x7fffu + ((u >> 16) & 1u);  // round-to-nearest-even
  return (uint16_t)(u >> 16);
}

// ---------------------------------------------------------------------------
// Fast math helpers (branch-free, restricted-range; inputs here are bounded)
// ---------------------------------------------------------------------------
__device__ __forceinline__ float rcpf_fast(float d) {
  float r = __builtin_amdgcn_rcpf(d);
  r = fmaf(r, fmaf(-d, r, 1.0f), r);  // 1 Newton -> ~1 ulp
  return r;
}

__device__ __forceinline__ double rcp64_fast(double y) {
  double r = __builtin_amdgcn_rcp(y);
  r = fma(r, fma(-y, r, 1.0), r);
  r = fma(r, fma(-y, r, 1.0), r);  // 2 Newton -> ~1e-16 rel
  return r;
}

// tanh via native exp2; abs err ~1e-6 for |a| <= ~40 (data gives |a| <~ 12)
__device__ __forceinline__ float tanhf_fast(float a) {
  float t = __expf(2.0f * a);
  float d = t + 1.0f;
  return fmaf(-2.0f, rcpf_fast(d), 1.0f);
}

// Short fp64 log: uniform relative error ~8e-8 (atanh series to t^7).
// sqrt2-folding avoids cancellation near x -> 1 (the u~1 Gumbel hazard).
__device__ __forceinline__ double flog64s(double xx) {
  long long b = __double_as_longlong(xx);
  int e = (int)(b >> 52) - 1023;
  double m = __longlong_as_double((b & 0xFFFFFFFFFFFFFLL) | 0x3FF0000000000000LL);
  if (m > 1.4142135623730951) { m *= 0.5; e += 1; }
  double t = (m - 1.0) * rcp64_fast(m + 1.0);
  double t2 = t * t;
  double p = fma(t2, fma(t2, 1.42857142857142857e-01, 2.0e-01),
                 3.33333333333333333e-01);
  double q = 2.0 * t;
  double lm = fma(q * t2, p, q);
  return fma((double)e, 6.93147180559945309e-01, lm);
}

// Full fp64 log: rel err ~1e-15 (series to t^13, split ln2).
__device__ __forceinline__ double flog64(double xx) {
  long long b = __double_as_longlong(xx);
  int e = (int)(b >> 52) - 1023;
  double m = __longlong_as_double((b & 0xFFFFFFFFFFFFFLL) | 0x3FF0000000000000LL);
  if (m > 1.4142135623730951) { m *= 0.5; e += 1; }
  double t = (m - 1.0) * rcp64_fast(m + 1.0);
  double t2 = t * t;
  double p = 7.69230769230769231e-02;          // 1/13
  p = fma(p, t2, 9.09090909090909091e-02);     // 1/11
  p = fma(p, t2, 1.11111111111111111e-01);     // 1/9
  p = fma(p, t2, 1.42857142857142857e-01);     // 1/7
  p = fma(p, t2, 2.0e-01);                     // 1/5
  p = fma(p, t2, 3.33333333333333333e-01);     // 1/3
  double q = 2.0 * t;
  double lm = fma(q * t2, p, q);
  double ed = (double)e;
  return fma(ed, 6.93147180369123816490e-01,
             fma(ed, 1.90821492927058770002e-10, lm));
}

// fp64 exp for |x| <= ~40; rel err ~2e-16 (Taylor-12 after 2-part ln2 reduce)
__device__ __forceinline__ double fexp64(double xx) {
  double t = xx * 1.44269504088896340736;
  double n = rint(t);
  double r = fma(-n, 6.93147180369123816490e-01, xx);
  r = fma(-n, 1.90821492927058770002e-10, r);
  double p = 2.08767569878680989792e-09;   // 1/12!
  p = fma(p, r, 2.50521083854417187751e-08);
  p = fma(p, r, 2.75573192239858906526e-07);
  p = fma(p, r, 2.75573192239858925110e-06);
  p = fma(p, r, 2.48015873015873015873e-05);
  p = fma(p, r, 1.98412698412698412698e-04);
  p = fma(p, r, 1.38888888888888894068e-03);
  p = fma(p, r, 8.33333333333333321769e-03);
  p = fma(p, r, 4.16666666666666666435e-02);
  p = fma(p, r, 1.66666666666666657415e-01);
  p = fma(p, r, 5.0e-01);
  p = fma(p, r, 1.0);
  p = fma(p, r, 1.0);
  int ni = (int)n;
  double s = __longlong_as_double((long long)(1023 + ni) << 52);
  return p * s;
}

__device__ __forceinline__ double tanh64_fast(double a) {
  double t = fexp64(2.0 * a);
  return fma(-2.0, rcp64_fast(t + 1.0), 1.0);
}

// ---------------------------------------------------------------------------
// Kernel 1: pack triz_w -> MFMA B-fragment bf16 (unchanged layout), plus
// block 640 stages transposed pol_w/enc_w and zeroes the fixup counter into
// the h-region scratch (h is dead until triz_kernel runs).
// ---------------------------------------------------------------------------
__global__ __launch_bounds__(256) void pack_w_kernel(
    const float* __restrict__ triz_w, uint16_t* __restrict__ wp,
    const float* __restrict__ pol_w, const float* __restrict__ enc_w,
    float* __restrict__ pwT, float* __restrict__ ewT, int* __restrict__ cnt) {
  if (blockIdx.x == 640) {
    for (int t = threadIdx.x; t < NEXP * HID; t += 256) {
      int e = t >> 6, j = t & 63;
      pwT[e * 64 + j] = pol_w[j * NEXP + e];       // pwT[e][j]
    }
    for (int t = threadIdx.x; t < 512; t += 256) {
      int j = t >> 3, d = t & 7;
      ewT[t] = (d < INP) ? enc_w[d * HID + j] : 0.0f;  // ewT[j][8] padded
    }
    if (threadIdx.x == 0) *cnt = 0;
    return;
  }
  int i = blockIdx.x * 256 + threadIdx.x;  // grid covers exactly 40*64*64
  int e = i >> 12;
  int rem = i & 4095;
  int k = rem >> 6;
  int f = rem & 63;
  int kk = k >> 4, kl = k & 15;
  int half = kl >> 3, j = kl & 7;
  int nt = f >> 5;
  int lane = half * 32 + (f & 31);
  int dst = ((((e * 4 + kk) * 2 + nt) * 64) + lane) * 8 + j;
  wp[dst] = f32_to_bf16(triz_w[i]);
}

// ---------------------------------------------------------------------------
// Kernel 2: encoder + policy, ONE THREAD PER ROW (no cross-lane ops).
// f32 fast path with fp64 inner-log for the Gumbel; rows whose top-2 gap is
// < MARGIN are appended to a list for the fp64 fixup kernel.
// ---------------------------------------------------------------------------
__global__ __launch_bounds__(256) void enc_policy_kernel(
    const float* __restrict__ x, const float* __restrict__ ewT,
    const float* __restrict__ enc_b, const float* __restrict__ pwT,
    const float* __restrict__ pol_b, uint16_t* __restrict__ z_bf16,
    int* __restrict__ actions_i, float* __restrict__ probs_out,
    float* __restrict__ actions_f, int* __restrict__ cnt,
    int* __restrict__ list) {
  // Per-thread logits slice in LDS; stride 41 -> bank = (9*tid+e)%32,
  // conflict-free (2 lanes/bank is free per m136).
  __shared__ float lgs[256 * 41];
  const int r = blockIdx.x * 256 + threadIdx.x;

  const float xv0 = x[r * INP + 0], xv1 = x[r * INP + 1],
              xv2 = x[r * INP + 2], xv3 = x[r * INP + 3],
              xv4 = x[r * INP + 4];

  // z_j = tanh(x . enc_w[:,j] + b_j), f32 fast path.
  float z[64];
#pragma unroll
  for (int j = 0; j < 64; ++j) {
    const float4 w = *reinterpret_cast<const float4*>(ewT + j * 8);
    const float w4 = ewT[j * 8 + 4];
    float a = enc_b[j];
    a = fmaf(xv0, w.x, a);
    a = fmaf(xv1, w.y, a);
    a = fmaf(xv2, w.z, a);
    a = fmaf(xv3, w.w, a);
    a = fmaf(xv4, w4, a);
    z[j] = tanhf_fast(a);
  }

  // Store z row (128 B contiguous per thread) as bf16.
  {
    uint32_t zb[32];
#pragma unroll
    for (int p = 0; p < 32; ++p)
      zb[p] = (uint32_t)f32_to_bf16(z[2 * p]) |
              ((uint32_t)f32_to_bf16(z[2 * p + 1]) << 16);
    uint4* zo = reinterpret_cast<uint4*>(z_bf16 + (size_t)r * HID);
#pragma unroll
    for (int q = 0; q < 8; ++q)
      zo[q] = make_uint4(zb[4 * q], zb[4 * q + 1], zb[4 * q + 2], zb[4 * q + 3]);
  }

  float* mylg = lgs + threadIdx.x * 41;
  float best = -1e30f, second = -1e30f;
  int bi = 0;
#pragma unroll 2
  for (int e = 0; e < NEXP; ++e) {
    // logits[e] = z . pol_w[:,e] + pol_b[e]  (pwT rows are wave-uniform)
    const float4* wp4 = reinterpret_cast<const float4*>(pwT + e * 64);
    float a0 = 0.f, a1 = 0.f, a2 = 0.f, a3 = 0.f;
#pragma unroll
    for (int q = 0; q < 16; ++q) {
      float4 w = wp4[q];
      a0 = fmaf(z[4 * q + 0], w.x, a0);
      a1 = fmaf(z[4 * q + 1], w.y, a1);
      a2 = fmaf(z[4 * q + 2], w.z, a2);
      a3 = fmaf(z[4 * q + 3], w.w, a3);
    }
    float lg = pol_b[e] + ((a0 + a1) + (a2 + a3));
    mylg[e] = lg;

    // Gumbel: threefry((0,1),(0, r*40+e)); inner log MUST be fp64 (u~1
    // cancellation), outer log safe in f32.
    uint32_t o0, o1;
    threefry2x32(0u, 1u, 0u, (uint32_t)r * NEXP + (uint32_t)e, o0, o1);
    uint32_t bits = o0 ^ o1;
    const float TINY = 1.17549435e-38f;
    float uf = __uint_as_float((bits >> 9) | 0x3f800000u) - 1.0f;
    uf = uf * (1.0f - TINY) + TINY;
    uf = fmaxf(uf, TINY);
    double v = -flog64s((double)uf);
    float g = -__logf((float)v);

    float val = lg + g;
    if (val > best) {
      second = best; best = val; bi = e;
    } else if (val > second) {
      second = val;
    }
  }

  actions_i[r] = bi;
  actions_f[r] = (float)bi;
  if (best - second < MARGIN) {  // borderline -> fp64 fixup
    int slot = atomicAdd(cnt, 1);
    if (slot < LISTCAP) list[slot] = r;
  }

  // softmax probs (f32; tolerance is large)
  float mx = -1e30f;
  for (int e = 0; e < NEXP; ++e) mx = fmaxf(mx, mylg[e]);
  float s = 0.f;
  for (int e = 0; e < NEXP; ++e) {
    float p = __expf(mylg[e] - mx);
    mylg[e] = p;
    s += p;
  }
  float inv = rcpf_fast(s);
  float4* po = reinterpret_cast<float4*>(probs_out + (size_t)r * NEXP);
  for (int k = 0; k < 10; ++k) {
    float4 pv;
    pv.x = mylg[4 * k + 0] * inv;
    pv.y = mylg[4 * k + 1] * inv;
    pv.z = mylg[4 * k + 2] * inv;
    pv.w = mylg[4 * k + 3] * inv;
    po[k] = pv;
  }
}

// ---------------------------------------------------------------------------
// Kernel 2b: fp64 fixup for borderline rows (expected ~350 of 131072).
// Reproduces the previous all-fp64 action path exactly (to ~1e-15).
// ---------------------------------------------------------------------------
__global__ __launch_bounds__(256) void fixup_kernel(
    const float* __restrict__ x, const float* __restrict__ ewT,
    const float* __restrict__ enc_b, const float* __restrict__ pwT,
    const float* __restrict__ pol_b, const int* __restrict__ cnt,
    const int* __restrict__ list, int* __restrict__ actions_i,
    float* __restrict__ actions_f) {
  int n = *cnt;
  if (n > LISTCAP) n = LISTCAP;
  for (int ii = blockIdx.x * blockDim.x + threadIdx.x; ii < n;
       ii += gridDim.x * blockDim.x) {
    int r = list[ii];
    double zd[64];
#pragma unroll
    for (int j = 0; j < 64; ++j) {
      double a = (double)enc_b[j];
#pragma unroll
      for (int d = 0; d < INP; ++d)
        a += (double)x[r * INP + d] * (double)ewT[j * 8 + d];
      zd[j] = tanh64_fast(a);
    }
    double best = -1.0e300;
    int bi = 0;
    for (int e = 0; e < NEXP; ++e) {
      double a0 = 0.0, a1 = 0.0, a2 = 0.0, a3 = 0.0;
#pragma unroll
      for (int j = 0; j < 64; j += 4) {
        a0 += zd[j + 0] * (double)pwT[e * 64 + j + 0];
        a1 += zd[j + 1] * (double)pwT[e * 64 + j + 1];
        a2 += zd[j + 2] * (double)pwT[e * 64 + j + 2];
        a3 += zd[j + 3] * (double)pwT[e * 64 + j + 3];
      }
      double lg = (double)pol_b[e] + ((a0 + a1) + (a2 + a3));
      uint32_t o0, o1;
      threefry2x32(0u, 1u, 0u, (uint32_t)r * NEXP + (uint32_t)e, o0, o1);
      uint32_t bits = o0 ^ o1;
      const float TINY = 1.17549435e-38f;
      float uf = __uint_as_float((bits >> 9) | 0x3f800000u) - 1.0f;
      uf = uf * (1.0f - TINY) + TINY;
      uf = fmaxf(uf, TINY);
      double v = -flog64((double)uf);
      double g = -flog64(v);
      double val = lg + g;
      if (val > best) { best = val; bi = e; }  // strict > = first occurrence
    }
    actions_i[r] = bi;
    actions_f[r] = (float)bi;
  }
}

// ---------------------------------------------------------------------------
// Kernel 3: h[b,e,f] = relu(z[b,:] @ triz_w[e,:,:] + triz_b[e,:])
// bf16 MFMA 32x32x16, A-fragments reused across experts. h stores are
// nontemporal (1.34 GB stream, 97.5% never re-read).
// ---------------------------------------------------------------------------
__global__ __launch_bounds__(256) void triz_kernel(
    const uint16_t* __restrict__ z_bf16, const uint16_t* __restrict__ wp,
    const float* __restrict__ triz_b, float* __restrict__ h) {
  const int lane = threadIdx.x & 63;
  const int wv = threadIdx.x >> 6;
  const int m0 = blockIdx.x * 128 + wv * 32;
  const int half = lane >> 5;
  const int col = lane & 31;

  const uint16_t* zr = z_bf16 + (size_t)(m0 + col) * HID + half * 8;
  bf16x8 A[4];
#pragma unroll
  for (int kk = 0; kk < 4; ++kk)
    A[kk] = *reinterpret_cast<const bf16x8*>(zr + kk * 16);

  float* hb = h + (size_t)(m0 + (half << 2)) * (NEXP * HID) + col;

  const bf16x8* wpv = reinterpret_cast<const bf16x8*>(wp);
  for (int e = 0; e < NEXP; ++e) {
    const bf16x8* wpe = wpv + (size_t)e * 512 + lane;
    f32x16 acc0 = {}, acc1 = {};
#pragma unroll
    for (int kk = 0; kk < 4; ++kk) {
      bf16x8 b0 = wpe[(kk * 2 + 0) * 64];
      bf16x8 b1 = wpe[(kk * 2 + 1) * 64];
      acc0 = __builtin_amdgcn_mfma_f32_32x32x16_bf16(A[kk], b0, acc0, 0, 0, 0);
      acc1 = __builtin_amdgcn_mfma_f32_32x32x16_bf16(A[kk], b1, acc1, 0, 0, 0);
    }
    float bv0 = triz_b[e * HID + col];
    float bv1 = triz_b[e * HID + 32 + col];
#pragma unroll
    for (int reg = 0; reg < 16; ++reg) {
      int row = (reg & 3) + ((reg >> 2) << 3);
      size_t off = (size_t)row * (NEXP * HID) + (size_t)e * HID;
      __builtin_nontemporal_store(fmaxf(acc0[reg] + bv0, 0.0f), &hb[off]);
      __builtin_nontemporal_store(fmaxf(acc1[reg] + bv1, 0.0f), &hb[off + 32]);
    }
  }
}

// ---------------------------------------------------------------------------
// Kernel 4: out[b,:] = h[b, action[b], :] @ dec_w + dec_b
// ---------------------------------------------------------------------------
__global__ __launch_bounds__(256) void decode_kernel(
    const float* __restrict__ h, const int* __restrict__ actions_i,
    const float* __restrict__ dec_w, const float* __restrict__ dec_b,
    float* __restrict__ out) {
  int b = blockIdx.x * 256 + threadIdx.x;
  if (b >= B_ROWS) return;
  int a = actions_i[b];
  const float4* hr =
      reinterpret_cast<const float4*>(h + ((size_t)b * NEXP + a) * HID);
  float acc0 = dec_b[0], acc1 = dec_b[1], acc2 = dec_b[2], acc3 = dec_b[3],
        acc4 = dec_b[4];
#pragma unroll
  for (int q = 0; q < 16; ++q) {
    float4 hv = hr[q];
#pragma unroll
    for (int t = 0; t < 4; ++t) {
      float v = (&hv.x)[t];
      int f = q * 4 + t;
      acc0 += v * dec_w[f * 5 + 0];
      acc1 += v * dec_w[f * 5 + 1];
      acc2 += v * dec_w[f * 5 + 2];
      acc3 += v * dec_w[f * 5 + 3];
      acc4 += v * dec_w[f * 5 + 4];
    }
  }
  float* o = out + (size_t)b * OUT_D;
  o[0] = acc0; o[1] = acc1; o[2] = acc2; o[3] = acc3; o[4] = acc4;
}

extern "C" void kernel_launch(void* const* d_in, const int* in_sizes, int n_in,
                              void* d_out, int out_size, void* d_ws,
                              size_t ws_size, hipStream_t stream) {
  const float* x = (const float*)d_in[0];
  const float* enc_w = (const float*)d_in[1];
  const float* enc_b = (const float*)d_in[2];
  const float* triz_w = (const float*)d_in[3];
  const float* triz_b = (const float*)d_in[4];
  const float* pol_w = (const float*)d_in[5];
  const float* pol_b = (const float*)d_in[6];
  const float* dec_w = (const float*)d_in[7];
  const float* dec_b = (const float*)d_in[8];

  // d_out: [B,5] out | [B,40] probs | [B] actions | [B,40,64] h  (all f32)
  float* out = (float*)d_out;
  float* probs = out + (size_t)B_ROWS * OUT_D;
  float* actions_f = probs + (size_t)B_ROWS * NEXP;
  float* h = actions_f + B_ROWS;

  // ws: z_bf16 (16 MiB) | wpack (320 KiB) | actions_i (512 KiB)
  uint8_t* ws = (uint8_t*)d_ws;
  uint16_t* z_bf16 = (uint16_t*)ws;
  uint16_t* wpack = (uint16_t*)(ws + (size_t)B_ROWS * HID * 2);
  int* actions_i =
      (int*)(ws + (size_t)B_ROWS * HID * 2 + (size_t)NEXP * HID * HID * 2);

  // Transient scratch lives at the head of the h region: it is written by
  // pack, read by enc/fixup, and only then overwritten by triz (stream order).
  float* pwT = h;                    // 2560 f32 (pol_w transposed [40][64])
  float* ewT = pwT + NEXP * HID;     // 512 f32 (enc_w transposed [64][8])
  int* cnt = (int*)(ewT + 512);      // fixup counter
  int* list = cnt + 1;               // fixup row list (<= LISTCAP)

  pack_w_kernel<<<641, 256, 0, stream>>>(triz_w, wpack, pol_w, enc_w, pwT,
                                         ewT, cnt);
  enc_policy_kernel<<<B_ROWS / 256, 256, 0, stream>>>(
      x, ewT, enc_b, pwT, pol_b, z_bf16, actions_i, probs, actions_f, cnt,
      list);
  fixup_kernel<<<32, 256, 0, stream>>>(x, ewT, enc_b, pwT, pol_b, cnt, list,
                                       actions_i, actions_f);
  triz_kernel<<<B_ROWS / 128, 256, 0, stream>>>(z_bf16, wpack, triz_b, h);
  decode_kernel<<<B_ROWS / 256, 256, 0, stream>>>(h, actions_i, dec_w, dec_b,
                                                  out);
}